// Round 1
// baseline (96.655 us; speedup 1.0000x reference)
//
#include <hip/hip_runtime.h>

#define BB   256       // batch
#define TT   16384     // time
#define WIN  5
#define HID  5
#define NN   (TT - WIN)   // 16379
#define NPAD 16384
#define TILE 256
#define NGROUPS 8
#define ROWS_PER_GROUP 32   // 256 / 8
#define STAGE_ROWS 8

// Kernel A: partial sum of squared errors per (group, n).
// mode 0: deterministic store to ws[g*NPAD + n]
// mode 1: atomicAdd into ws[n] (ws[0..NN) pre-zeroed)
__global__ __launch_bounds__(TILE)
void loss_partial(const float* __restrict__ series,
                  const float* __restrict__ weight,
                  const float* __restrict__ bias,
                  float* __restrict__ ws, int mode) {
    const int tid = threadIdx.x;
    const int n0  = blockIdx.x * TILE;
    const int g   = blockIdx.y;
    const int b0  = g * ROWS_PER_GROUP;
    const int n   = n0 + tid;

    // weight/bias into registers (uniform loads -> scalar loads)
    float w[HID][WIN], bi[HID];
#pragma unroll
    for (int h = 0; h < HID; ++h) {
        bi[h] = bias[h];
#pragma unroll
        for (int v = 0; v < WIN; ++v) w[h][v] = weight[h * WIN + v];
    }

    __shared__ float lds[STAGE_ROWS][TILE + 8];  // need TILE+5 cols, pad to 264

    float acc = 0.f;
    for (int rs = 0; rs < ROWS_PER_GROUP; rs += STAGE_ROWS) {
        __syncthreads();
#pragma unroll
        for (int r = 0; r < STAGE_ROWS; ++r) {
            const int b = b0 + rs + r;
            const float* src = series + (size_t)b * TT + n0;
            if (n0 + tid < TT) lds[r][tid] = src[tid];
            if (tid < WIN) {
                int c = TILE + tid;
                if (n0 + c < TT) lds[r][c] = src[c];
            }
        }
        __syncthreads();
        if (n < NN) {
#pragma unroll
            for (int r = 0; r < STAGE_ROWS; ++r) {
                float s[WIN + 1];
#pragma unroll
                for (int j = 0; j <= WIN; ++j) s[j] = lds[r][tid + j];
#pragma unroll
                for (int h = 0; h < HID; ++h) {
                    float t = bi[h];
#pragma unroll
                    for (int v = 0; v < WIN; ++v) t = fmaf(s[v], w[h][v], t);
                    float e = t - s[h + 1];
                    acc = fmaf(e, e, acc);
                }
            }
        }
    }
    if (n < NN) {
        if (mode == 0) ws[(size_t)g * NPAD + n] = acc;
        else atomicAdd(ws + n, acc);
    }
}

// Kernel B: reduce partials, scale, diffs, mask.
__global__ __launch_bounds__(256)
void finalize(const float* __restrict__ ws, int ngroups,
              const float* __restrict__ thr_ptr,
              float* __restrict__ out) {
    const int i = blockIdx.x * blockDim.x + threadIdx.x;
    if (i >= NN) return;
    const float inv = 1.0f / (float)(BB * HID);
    float s = 0.f;
    for (int g = 0; g < ngroups; ++g) s += ws[(size_t)g * NPAD + i];
    const float li = s * inv;
    out[i] = li;
    if (i < NN - 1) {
        float s1 = 0.f;
        for (int g = 0; g < ngroups; ++g) s1 += ws[(size_t)g * NPAD + i + 1];
        const float li1 = s1 * inv;
        const float d = fabsf(li1 - li);
        out[NN + i] = d;
        const float thr = *thr_ptr;
        out[NN + (NN - 1) + i] = (d > thr) ? 1.0f : 0.0f;
    }
}

extern "C" void kernel_launch(void* const* d_in, const int* in_sizes, int n_in,
                              void* d_out, int out_size, void* d_ws, size_t ws_size,
                              hipStream_t stream) {
    const float* series = (const float*)d_in[0];
    const float* weight = (const float*)d_in[1];
    const float* bias   = (const float*)d_in[2];
    const float* thr    = (const float*)d_in[3];
    float* out = (float*)d_out;
    float* ws  = (float*)d_ws;

    const int n_tiles = (NN + TILE - 1) / TILE;  // 64
    const size_t need_det = (size_t)NGROUPS * NPAD * sizeof(float);  // 512 KB

    if (ws_size >= need_det) {
        dim3 grid(n_tiles, NGROUPS);
        loss_partial<<<grid, TILE, 0, stream>>>(series, weight, bias, ws, 0);
        finalize<<<(NN + 255) / 256, 256, 0, stream>>>(ws, NGROUPS, thr, out);
    } else {
        hipMemsetAsync(d_ws, 0, (size_t)NPAD * sizeof(float), stream);
        dim3 grid(n_tiles, NGROUPS);
        loss_partial<<<grid, TILE, 0, stream>>>(series, weight, bias, ws, 1);
        finalize<<<(NN + 255) / 256, 256, 0, stream>>>(ws, 1, thr, out);
    }
}

// Round 2
// 85.988 us; speedup vs baseline: 1.1240x; 1.1240x over previous
//
#include <hip/hip_runtime.h>

#define BB    256       // batch
#define TT    16384     // time
#define WIN   5
#define HID   5
#define NN    (TT - WIN)     // 16379 losses; NN-1 = 16378 diffs/mask
#define TILE  32             // loss columns owned per block
#define NT    512            // TILE*NT = 16384 >= NN
#define SROWS 64             // batch rows staged per stage (4 stages)
#define NCOLS (TILE + WIN + 1)   // 38 staged columns (need c..c+5 for c<=32)
#define LDSW  41                 // odd leading dim -> conflict-free column reads

// One fused kernel: losses + diffs + mask. No workspace, no second dispatch.
__global__ __launch_bounds__(256)
void llsa_fused(const float* __restrict__ series,
                const float* __restrict__ weight,
                const float* __restrict__ bias,
                const float* __restrict__ thr_ptr,
                float* __restrict__ out) {
    const int tid  = threadIdx.x;
    const int n0   = blockIdx.x * TILE;
    const int c    = tid & (TILE - 1);   // owned column 0..31
    const int rsub = tid >> 5;           // row sub-group 0..7

    // uniform weights/bias -> scalar loads
    float w[HID][WIN], bi[HID];
#pragma unroll
    for (int h = 0; h < HID; ++h) {
        bi[h] = bias[h];
#pragma unroll
        for (int v = 0; v < WIN; ++v) w[h][v] = weight[h * WIN + v];
    }

    __shared__ float lds[SROWS * LDSW];      // 64 x 41 floats = 10.5 KB
    __shared__ float psum[8 * TILE];         // phase-1 partials
    __shared__ float Ls[TILE + 1];           // scaled losses incl. boundary col

    float acc  = 0.f;   // phase-1: this thread's 32 rows for column c
    float bacc = 0.f;   // boundary column n0+TILE, rows tid (wave 0 only)

    for (int stage = 0; stage < BB / SROWS; ++stage) {
        const int b0 = stage * SROWS;
        __syncthreads();
        // stage SROWS x NCOLS into LDS, coalesced-ish (row segments of 152B)
        for (int idx = tid; idx < SROWS * NCOLS; idx += 256) {
            const int r   = idx / NCOLS;
            const int cc  = idx - r * NCOLS;
            const int col = n0 + cc;
            float v = (col < TT) ? series[(size_t)(b0 + r) * TT + col] : 0.f;
            lds[r * LDSW + cc] = v;
        }
        __syncthreads();

        // phase 1: 8 rows per thread for owned column c
#pragma unroll
        for (int k = 0; k < 8; ++k) {
            const float* row = &lds[(rsub * 8 + k) * LDSW + c];
            float sv[WIN + 1];
#pragma unroll
            for (int j = 0; j <= WIN; ++j) sv[j] = row[j];
#pragma unroll
            for (int h = 0; h < HID; ++h) {
                float t = bi[h];
#pragma unroll
                for (int v = 0; v < WIN; ++v) t = fmaf(sv[v], w[h][v], t);
                const float e = t - sv[h + 1];
                acc = fmaf(e, e, acc);
            }
        }

        // phase 2 (wave 0 only): boundary column n0+TILE, one row per lane
        if (tid < SROWS) {
            const float* row = &lds[tid * LDSW + TILE];
            float sv[WIN + 1];
#pragma unroll
            for (int j = 0; j <= WIN; ++j) sv[j] = row[j];
#pragma unroll
            for (int h = 0; h < HID; ++h) {
                float t = bi[h];
#pragma unroll
                for (int v = 0; v < WIN; ++v) t = fmaf(sv[v], w[h][v], t);
                const float e = t - sv[h + 1];
                bacc = fmaf(e, e, bacc);
            }
        }
    }

    // reduce boundary partials within wave 0 (other waves hold 0)
    float bs = bacc;
#pragma unroll
    for (int off = 32; off >= 1; off >>= 1) bs += __shfl_down(bs, off);

    psum[rsub * TILE + c] = acc;
    __syncthreads();

    const float inv = 1.0f / (float)(BB * HID);
    if (tid == 0) Ls[TILE] = bs * inv;
    if (tid < TILE) {
        float s = 0.f;
#pragma unroll
        for (int g = 0; g < 8; ++g) s += psum[g * TILE + tid];
        Ls[tid] = s * inv;
    }
    __syncthreads();

    if (tid < TILE) {
        const int i = n0 + tid;
        if (i < NN) {
            const float li = Ls[tid];
            out[i] = li;
            if (i < NN - 1) {
                const float d = fabsf(Ls[tid + 1] - li);
                out[NN + i] = d;
                out[2 * NN - 1 + i] = (d > thr_ptr[0]) ? 1.0f : 0.0f;
            }
        }
    }
}

extern "C" void kernel_launch(void* const* d_in, const int* in_sizes, int n_in,
                              void* d_out, int out_size, void* d_ws, size_t ws_size,
                              hipStream_t stream) {
    const float* series = (const float*)d_in[0];
    const float* weight = (const float*)d_in[1];
    const float* bias   = (const float*)d_in[2];
    const float* thr    = (const float*)d_in[3];
    float* out = (float*)d_out;
    (void)d_ws; (void)ws_size; (void)in_sizes; (void)n_in; (void)out_size;

    llsa_fused<<<NT, 256, 0, stream>>>(series, weight, bias, thr, out);
}

// Round 3
// 75.243 us; speedup vs baseline: 1.2846x; 1.1428x over previous
//
#include <hip/hip_runtime.h>

#define BB    256        // batch
#define TT    16384      // time
#define WIN   5
#define HID   5
#define NN    (TT - WIN)     // 16379 losses; NN-1 diffs/mask
#define TILE  32             // loss columns owned per block
#define NT    512            // TILE*NT = 16384 >= NN
#define NCOLS (TILE + WIN + 1)   // 38 staged columns
#define LDSW  44                 // mult of 4 (b128-aligned writes), low conflicts

// Single fused kernel: losses + diffs + mask. All 256 batch rows staged once.
__global__ __launch_bounds__(256)
void llsa_fused(const float* __restrict__ series,
                const float* __restrict__ weight,
                const float* __restrict__ bias,
                const float* __restrict__ thr_ptr,
                float* __restrict__ out) {
    const int tid = threadIdx.x;
    // XCD swizzle: physical block p -> tile t so XCD (p%8) owns a contiguous
    // 64-tile (2048-col) span; halo lines become same-XCD L2 hits.
    const int t  = (blockIdx.x & 7) * 64 + (blockIdx.x >> 3);
    const int n0 = t * TILE;

    // uniform weights/bias -> scalar regs
    float w[HID][WIN], bi[HID];
#pragma unroll
    for (int h = 0; h < HID; ++h) {
        bi[h] = bias[h];
#pragma unroll
        for (int v = 0; v < WIN; ++v) w[h][v] = weight[h * WIN + v];
    }

    __shared__ float lds[BB * LDSW];     // 256 x 44 floats = 45 KB
    __shared__ float psum[8 * TILE];
    __shared__ float Ls[TILE + 1];

    // ---- stage all 256 rows x 38 cols ----
    // Pass A: owned 32 cols as aligned float4 (one 128B line per row, no overfetch)
    {
        const int c4 = (tid & 7) * 4;        // 0,4,...,28
        const int rb = tid >> 3;             // 0..31
#pragma unroll
        for (int it = 0; it < 8; ++it) {
            const int r = it * 32 + rb;
            const float4 v = *(const float4*)(series + (size_t)r * TT + n0 + c4);
            *(float4*)(&lds[r * LDSW + c4]) = v;
        }
    }
    // Pass B: 6-col halo, one row per thread (neighbor tile's line -> L2 hit)
    {
        const float* row = series + (size_t)tid * TT;
#pragma unroll
        for (int j = 0; j < WIN + 1; ++j) {
            const int col = n0 + TILE + j;
            lds[tid * LDSW + TILE + j] = (col < TT) ? row[col] : 0.f;
        }
    }
    __syncthreads();

    // ---- phase 1: owned column c, 32 rows per thread, row-paired (float2) ----
    const int c    = tid & (TILE - 1);
    const int rsub = tid >> 5;               // 8 subgroups x 32 rows
    float ax = 0.f, ay = 0.f;
#pragma unroll
    for (int k = 0; k < 32; k += 2) {
        const float* rA = &lds[(rsub * 32 + k) * LDSW + c];
        const float* rB = rA + LDSW;
        float sx[WIN + 1], sy[WIN + 1];
#pragma unroll
        for (int j = 0; j <= WIN; ++j) { sx[j] = rA[j]; sy[j] = rB[j]; }
#pragma unroll
        for (int h = 0; h < HID; ++h) {
            float tx = bi[h], ty = bi[h];
#pragma unroll
            for (int v = 0; v < WIN; ++v) {
                tx = fmaf(sx[v], w[h][v], tx);
                ty = fmaf(sy[v], w[h][v], ty);
            }
            const float ex = tx - sx[h + 1];
            const float ey = ty - sy[h + 1];
            ax = fmaf(ex, ex, ax);
            ay = fmaf(ey, ey, ay);
        }
    }
    const float acc = ax + ay;

    // ---- phase 2 (wave 0): boundary column n0+TILE, 4 rows per lane ----
    float bacc = 0.f;
    if (tid < 64) {
#pragma unroll
        for (int s = 0; s < 4; ++s) {
            const float* row = &lds[(tid + 64 * s) * LDSW + TILE];
            float sv[WIN + 1];
#pragma unroll
            for (int j = 0; j <= WIN; ++j) sv[j] = row[j];
#pragma unroll
            for (int h = 0; h < HID; ++h) {
                float tt = bi[h];
#pragma unroll
                for (int v = 0; v < WIN; ++v) tt = fmaf(sv[v], w[h][v], tt);
                const float e = tt - sv[h + 1];
                bacc = fmaf(e, e, bacc);
            }
        }
    }
    float bs = bacc;
#pragma unroll
    for (int off = 32; off >= 1; off >>= 1) bs += __shfl_down(bs, off);

    psum[rsub * TILE + c] = acc;
    __syncthreads();

    const float inv = 1.0f / (float)(BB * HID);
    if (tid == 0) Ls[TILE] = bs * inv;
    if (tid < TILE) {
        float s = 0.f;
#pragma unroll
        for (int g = 0; g < 8; ++g) s += psum[g * TILE + tid];
        Ls[tid] = s * inv;
    }
    __syncthreads();

    if (tid < TILE) {
        const int i = n0 + tid;
        if (i < NN) {
            const float li = Ls[tid];
            out[i] = li;
            if (i < NN - 1) {
                const float d = fabsf(Ls[tid + 1] - li);
                out[NN + i] = d;
                out[2 * NN - 1 + i] = (d > thr_ptr[0]) ? 1.0f : 0.0f;
            }
        }
    }
}

extern "C" void kernel_launch(void* const* d_in, const int* in_sizes, int n_in,
                              void* d_out, int out_size, void* d_ws, size_t ws_size,
                              hipStream_t stream) {
    const float* series = (const float*)d_in[0];
    const float* weight = (const float*)d_in[1];
    const float* bias   = (const float*)d_in[2];
    const float* thr    = (const float*)d_in[3];
    float* out = (float*)d_out;
    (void)d_ws; (void)ws_size; (void)in_sizes; (void)n_in; (void)out_size;

    llsa_fused<<<NT, 256, 0, stream>>>(series, weight, bias, thr, out);
}

// Round 5
// 73.097 us; speedup vs baseline: 1.3223x; 1.0294x over previous
//
#include <hip/hip_runtime.h>

#define BB    256        // batch
#define TT    16384      // time
#define WIN   5
#define HID   5
#define NN    (TT - WIN)     // 16379 losses; NN-1 diffs/mask
#define TILE  32             // loss columns owned per block
#define NT    512            // TILE*NT = 16384 >= NN
#define LDSW  44             // staged row stride (>=40 cols), mult of 4 for b128

// Single fused kernel: losses + diffs + mask. All 256 batch rows staged once.
// Phase 1 reads LDS as 3x ds_read_b128 per row (column-quad ownership).
__global__ __launch_bounds__(256)
void llsa_fused(const float* __restrict__ series,
                const float* __restrict__ weight,
                const float* __restrict__ bias,
                const float* __restrict__ thr_ptr,
                float* __restrict__ out) {
    const int tid = threadIdx.x;
    // XCD swizzle: XCD (p%8) owns a contiguous 64-tile (2048-col) span;
    // halo lines (cols 32..39 = neighbor's first line) become same-XCD L2 hits.
    const int t  = (blockIdx.x & 7) * 64 + (blockIdx.x >> 3);
    const int n0 = t * TILE;

    float w[HID][WIN], bi[HID];
#pragma unroll
    for (int h = 0; h < HID; ++h) {
        bi[h] = bias[h];
#pragma unroll
        for (int v = 0; v < WIN; ++v) w[h][v] = weight[h * WIN + v];
    }

    __shared__ float lds[BB * LDSW];       // 256 x 44 floats = 44 KB
    __shared__ float psum[32 * 33];        // padded: column reads conflict-free
    __shared__ float Ls[TILE + 1];

    // ---- stage 256 rows x 40 cols ----
    // Pass A1: cols 0..31, aligned float4 (one 128B line per row, zero overfetch)
    {
        const int c4 = (tid & 7) * 4;       // 0..28
        const int rb = tid >> 3;            // 0..31
#pragma unroll
        for (int it = 0; it < 8; ++it) {
            const int r = it * 32 + rb;
            const float4 v = *(const float4*)(series + (size_t)r * TT + n0 + c4);
            *(float4*)(&lds[r * LDSW + c4]) = v;
        }
    }
    // Pass A2: cols 32..39 (halo, neighbor tile's first line -> L2 hit)
    {
#pragma unroll
        for (int it = 0; it < 2; ++it) {
            const int idx = it * 256 + tid;
            const int r   = idx >> 1;
            const int cc  = 32 + (idx & 1) * 4;
            const int col = n0 + cc;
            float4 v = make_float4(0.f, 0.f, 0.f, 0.f);
            if (col + 3 < TT) {             // false only for the last tile
                v = *(const float4*)(series + (size_t)r * TT + col);
            }
            *(float4*)(&lds[r * LDSW + cc]) = v;
        }
    }
    __syncthreads();

    // ---- phase 1: column quad 4cq..4cq+3, rows rs*8..rs*8+7, b128 LDS reads ----
    const int cq = tid & 7;                 // 8 column-quads
    const int rs = tid >> 3;                // 32 row subgroups x 8 rows
    float a0 = 0.f, a1 = 0.f, a2 = 0.f, a3 = 0.f;
#pragma unroll
    for (int k = 0; k < 8; ++k) {
        const float* row = &lds[(rs * 8 + k) * LDSW + 4 * cq];
        const float4 f0 = *(const float4*)(row);
        const float4 f1 = *(const float4*)(row + 4);
        const float4 f2 = *(const float4*)(row + 8);
        const float s[12] = { f0.x, f0.y, f0.z, f0.w,
                              f1.x, f1.y, f1.z, f1.w,
                              f2.x, f2.y, f2.z, f2.w };
#pragma unroll
        for (int j = 0; j < 4; ++j) {
            float aj = 0.f;
#pragma unroll
            for (int h = 0; h < HID; ++h) {
                float tt = bi[h];
#pragma unroll
                for (int v = 0; v < WIN; ++v) tt = fmaf(s[j + v], w[h][v], tt);
                const float e = tt - s[j + h + 1];
                aj = fmaf(e, e, aj);
            }
            if (j == 0) a0 += aj; else if (j == 1) a1 += aj;
            else if (j == 2) a2 += aj; else a3 += aj;
        }
    }

    // ---- phase 2 (wave 0): boundary column n0+32, 4 rows per lane ----
    float bacc = 0.f;
    if (tid < 64) {
#pragma unroll
        for (int sIt = 0; sIt < 4; ++sIt) {
            const float* row = &lds[(tid + 64 * sIt) * LDSW + TILE];
            float sv[WIN + 1];
#pragma unroll
            for (int j = 0; j <= WIN; ++j) sv[j] = row[j];
#pragma unroll
            for (int h = 0; h < HID; ++h) {
                float tt = bi[h];
#pragma unroll
                for (int v = 0; v < WIN; ++v) tt = fmaf(sv[v], w[h][v], tt);
                const float e = tt - sv[h + 1];
                bacc = fmaf(e, e, bacc);
            }
        }
    }
    float bs = bacc;
#pragma unroll
    for (int off = 32; off >= 1; off >>= 1) bs += __shfl_down(bs, off);

    // ---- reduce partials across row subgroups ----
    psum[rs * 33 + 4 * cq + 0] = a0;
    psum[rs * 33 + 4 * cq + 1] = a1;
    psum[rs * 33 + 4 * cq + 2] = a2;
    psum[rs * 33 + 4 * cq + 3] = a3;
    const float inv = 1.0f / (float)(BB * HID);
    if (tid == 0) Ls[TILE] = bs * inv;
    __syncthreads();

    if (tid < TILE) {
        float s = 0.f;
#pragma unroll
        for (int r = 0; r < 32; ++r) s += psum[r * 33 + tid];
        Ls[tid] = s * inv;
    }
    __syncthreads();

    if (tid < TILE) {
        const int i = n0 + tid;
        if (i < NN) {
            const float li = Ls[tid];
            out[i] = li;
            if (i < NN - 1) {
                const float d = fabsf(Ls[tid + 1] - li);
                out[NN + i] = d;
                out[2 * NN - 1 + i] = (d > thr_ptr[0]) ? 1.0f : 0.0f;
            }
        }
    }
}

extern "C" void kernel_launch(void* const* d_in, const int* in_sizes, int n_in,
                              void* d_out, int out_size, void* d_ws, size_t ws_size,
                              hipStream_t stream) {
    const float* series = (const float*)d_in[0];
    const float* weight = (const float*)d_in[1];
    const float* bias   = (const float*)d_in[2];
    const float* thr    = (const float*)d_in[3];
    float* out = (float*)d_out;
    (void)d_ws; (void)ws_size; (void)in_sizes; (void)n_in; (void)out_size;

    llsa_fused<<<NT, 256, 0, stream>>>(series, weight, bias, thr, out);
}